// Round 12
// baseline (431.970 us; speedup 1.0000x reference)
//
#include <hip/hip_runtime.h>
#include <math.h>

#define FF 128     // feature width (all layers)
#define CAP 32     // slots per (relation,node); Poisson(4) => P(deg>32) ~ 1e-19
#define GB 512     // gemm blocks inside setup_fused

typedef _Float16 half2v __attribute__((ext_vector_type(2)));
typedef _Float16 f16x8  __attribute__((ext_vector_type(8)));
typedef __fp16   fp16x2 __attribute__((ext_vector_type(2)));
typedef __attribute__((ext_vector_type(4))) float f4v;

__device__ __forceinline__ half2v u2h(unsigned u) {
    union { unsigned u; half2v h; } c; c.u = u; return c.h;
}
__device__ __forceinline__ unsigned h2u(half2v h) {
    union { unsigned u; half2v h; } c; c.h = h; return c.u;
}
__device__ __forceinline__ unsigned short f2h(float f) {
    _Float16 h = (_Float16)f;
    unsigned short u; __builtin_memcpy(&u, &h, 2); return u;
}
__device__ __forceinline__ half2v pk2h(float e) {
    union { fp16x2 p; half2v h; } c;
    c.p = __builtin_amdgcn_cvt_pkrtz(e, e);
    return c.h;
}
__device__ __forceinline__ float dot2(half2v a, half2v b, float c) {
#if __has_builtin(__builtin_amdgcn_fdot2)
    union { half2v h; fp16x2 p; } ca, cb;
    ca.h = a; cb.h = b;
    return __builtin_amdgcn_fdot2(ca.p, cb.p, c, false);
#else
    return c + (float)a.x * (float)b.x + (float)a.y * (float)b.y;
#endif
}
// packed-f16 shfl_xor add: v += shfl_xor(v, mask)
__device__ __forceinline__ half2v shfladd_h(half2v v, int mask) {
    return v + u2h(__shfl_xor(h2u(v), mask));
}

// =====================================================================
// Fused setup dispatch. Role INTERLEAVED so gemm + csr are co-resident
// from t=0 (R11 range-partition serialized them: first 512 resident
// blocks were all gemm):
//   blockIdx < 1024 : even -> gemm block b=idx/2 (512), odd -> csr b=idx/2
//   then            : csr blocks GB..CB-1, pack_W (1536), pack_att (3)
// =====================================================================
__global__ __launch_bounds__(256, 2) void setup_fused(
    // gemm0
    const float* __restrict__ x,
    const float* __restrict__ W0s_, const float* __restrict__ bs0,
    const float* __restrict__ W0d_, const float* __restrict__ bd0,
    unsigned short* __restrict__ fs_all, unsigned short* __restrict__ fd_all,
    int nrb, int n,
    // csr
    const int* __restrict__ esrc_all, const int* __restrict__ edst_all,
    int* __restrict__ cursor, int* __restrict__ slots, int totalE, int ne,
    // pack W
    const float* __restrict__ W1s_, const float* __restrict__ W1d_,
    const float* __restrict__ W2s_, const float* __restrict__ W2d_,
    unsigned short* __restrict__ Wp,
    // pack att
    const float* __restrict__ a0, const float* __restrict__ a1,
    const float* __restrict__ a2, unsigned* __restrict__ attH,
    int CB)
{
    const int tid = threadIdx.x;
    int role, b;
    if (blockIdx.x < 2 * GB) {
        role = blockIdx.x & 1;            // 0 = gemm, 1 = csr
        b = blockIdx.x >> 1;
    } else {
        int rest = blockIdx.x - 2 * GB;
        const int csrRest = CB - GB;      // CB >= GB required (782 >= 512)
        if (rest < csrRest) { role = 1; b = GB + rest; }
        else {
            rest -= csrRest;
            if (rest < 1536) { role = 2; b = rest; }
            else             { role = 3; b = rest - 1536; }
        }
    }

    if (role == 0) {
        // ---------------- layer-0 GEMM (f32 inputs) ----------------
        const int wave = tid >> 6, lane = tid & 63;
        const int r = b & 3;
        const int half = wave & 1;
        const int lo = lane & 15, quad = lane >> 4;

        unsigned short* fs = fs_all + (size_t)r * n * FF;
        unsigned short* fd = fd_all + (size_t)r * n * FF;

        f16x8 B[2][4][4];
        #pragma unroll
        for (int mat = 0; mat < 2; ++mat) {
            const float* W = (mat == 0) ? W0s_ : W0d_;
            #pragma unroll
            for (int nbi = 0; nbi < 4; ++nbi)
                #pragma unroll
                for (int ks = 0; ks < 4; ++ks) {
                    const int nn = (half * 4 + nbi) * 16 + lo;
                    f16x8 v;
                    #pragma unroll
                    for (int j = 0; j < 8; ++j) {
                        const int k = ks * 32 + quad * 8 + j;
                        v[j] = (_Float16)W[((size_t)r * FF + k) * FF + nn];
                    }
                    B[mat][nbi][ks] = v;
                }
        }

        float biasS[4], biasD[4];
        #pragma unroll
        for (int nbi = 0; nbi < 4; ++nbi) {
            biasS[nbi] = bs0[r * FF + (half * 4 + nbi) * 16 + lo];
            biasD[nbi] = bd0[r * FF + (half * 4 + nbi) * 16 + lo];
        }

        const int stride = (GB >> 2) * 2;
        for (int rb = (b >> 2) * 2 + (wave >> 1); rb < nrb; rb += stride) {
            const int row0 = rb * 16;
            f16x8 A[4];
            #pragma unroll
            for (int ks = 0; ks < 4; ++ks) {
                const float* ap = &x[(size_t)(row0 + lo) * FF + ks * 32 + quad * 8];
                const float4 p0 = *(const float4*)&ap[0];
                const float4 p1 = *(const float4*)&ap[4];
                f16x8 v;
                v[0] = (_Float16)p0.x; v[1] = (_Float16)p0.y;
                v[2] = (_Float16)p0.z; v[3] = (_Float16)p0.w;
                v[4] = (_Float16)p1.x; v[5] = (_Float16)p1.y;
                v[6] = (_Float16)p1.z; v[7] = (_Float16)p1.w;
                A[ks] = v;
            }

            f4v cS[4], cD[4];
            #pragma unroll
            for (int nbi = 0; nbi < 4; ++nbi) {
                cS[nbi] = (f4v){biasS[nbi], biasS[nbi], biasS[nbi], biasS[nbi]};
                cD[nbi] = (f4v){biasD[nbi], biasD[nbi], biasD[nbi], biasD[nbi]};
            }

            #pragma unroll
            for (int ks = 0; ks < 4; ++ks)
                #pragma unroll
                for (int nbi = 0; nbi < 4; ++nbi) {
                    cS[nbi] = __builtin_amdgcn_mfma_f32_16x16x32_f16(
                        A[ks], B[0][nbi][ks], cS[nbi], 0, 0, 0);
                    cD[nbi] = __builtin_amdgcn_mfma_f32_16x16x32_f16(
                        A[ks], B[1][nbi][ks], cD[nbi], 0, 0, 0);
                }

            #pragma unroll
            for (int nbi = 0; nbi < 4; ++nbi)
                #pragma unroll
                for (int i = 0; i < 4; ++i) {
                    const size_t o = (size_t)(row0 + quad * 4 + i) * FF
                                   + (half * 4 + nbi) * 16 + lo;
                    fs[o] = f2h(cS[nbi][i]);
                    fd[o] = f2h(cD[nbi][i]);
                }
        }
        return;
    }

    if (role == 1) {
        // ---------------- padded-CSR fill, 4 independent chains/thread ----
        const int t0 = b * 1024 + tid;
        #pragma unroll
        for (int k = 0; k < 4; ++k) {
            const int i = t0 + k * 256;
            if (i < totalE) {
                const int r = i / ne;
                const int rd = r * n + edst_all[i];
                const int idx = atomicAdd(&cursor[rd], 1);
                slots[(size_t)rd * CAP + idx] = esrc_all[i];
            }
        }
        return;
    }

    if (role == 2) {
        // ---------------- pack W (all 3 layers) ----------------
        const int t = b * 256 + tid;
        if (t >= 3 * 4 * 2 * FF * FF) return;
        const int l    = t >> 17;
        const int rest = t & 131071;
        const int r    = rest >> 15;
        const int mat  = (rest >> 14) & 1;
        const int idx  = rest & 16383;
        const int k = idx >> 7, nn = idx & 127;
        const float* W = (l == 0) ? (mat ? W0d_ : W0s_)
                       : (l == 1) ? (mat ? W1d_ : W1s_)
                                  : (mat ? W2d_ : W2s_);
        const float v = W[((size_t)r * FF + k) * FF + nn];
        const int nb = nn >> 4, lo = nn & 15;
        const int ks = k >> 5, quad = (k >> 3) & 3, j = k & 7;
        const int lane = quad * 16 + lo;
        const size_t o = (((((((size_t)l * 4 + r) * 2 + mat) * 8 + nb) * 4 + ks) * 64 + lane) * 8) + j;
        Wp[o] = f2h(v);
        return;
    }

    // ---------------- pack att ----------------
    const int t = b * 256 + tid;
    if (t >= 768) return;
    const int l = t >> 8, rest = t & 255;
    const float* a = (l == 0) ? a0 : (l == 1) ? a1 : a2;
    const float2 v = ((const float2*)a)[rest];
    half2v h = {(_Float16)v.x, (_Float16)v.y};
    attH[t] = h2u(h);
}

// =====================================================================
// Batched MFMA GEMM over all 4 relations, f16 inputs (layers 1,2).
// Verified R8/R9, unchanged.
// =====================================================================
__global__ __launch_bounds__(256, 2) void mfma_gemm(
    const unsigned short* __restrict__ hb,
    const unsigned short* __restrict__ Wp,
    const float* __restrict__ bs_all,
    const float* __restrict__ bd_all,
    unsigned short* __restrict__ fs_all,
    unsigned short* __restrict__ fd_all,
    int nrb, int n)
{
    const int wave = threadIdx.x >> 6, lane = threadIdx.x & 63;
    const int r = blockIdx.x & 3;
    const int half = wave & 1;
    const int lo = lane & 15, quad = lane >> 4;

    const unsigned short* Wr = Wp + (size_t)r * 2 * FF * FF;
    unsigned short* fs = fs_all + (size_t)r * n * FF;
    unsigned short* fd = fd_all + (size_t)r * n * FF;

    f16x8 B[2][4][4];
    #pragma unroll
    for (int mat = 0; mat < 2; ++mat)
        #pragma unroll
        for (int nbi = 0; nbi < 4; ++nbi)
            #pragma unroll
            for (int ks = 0; ks < 4; ++ks) {
                const int nb = half * 4 + nbi;
                B[mat][nbi][ks] = *(const f16x8*)
                    &Wr[(((((size_t)mat * 8 + nb) * 4 + ks) * 64 + lane) * 8)];
            }

    float biasS[4], biasD[4];
    #pragma unroll
    for (int nbi = 0; nbi < 4; ++nbi) {
        biasS[nbi] = bs_all[r * FF + (half * 4 + nbi) * 16 + lo];
        biasD[nbi] = bd_all[r * FF + (half * 4 + nbi) * 16 + lo];
    }

    const int stride = (gridDim.x >> 2) * 2;
    for (int rb = (blockIdx.x >> 2) * 2 + (wave >> 1); rb < nrb; rb += stride) {
        const int row0 = rb * 16;
        f16x8 A[4];
        #pragma unroll
        for (int ks = 0; ks < 4; ++ks)
            A[ks] = *(const f16x8*)&hb[(size_t)(row0 + lo) * FF + ks * 32 + quad * 8];

        f4v cS[4], cD[4];
        #pragma unroll
        for (int nbi = 0; nbi < 4; ++nbi) {
            cS[nbi] = (f4v){biasS[nbi], biasS[nbi], biasS[nbi], biasS[nbi]};
            cD[nbi] = (f4v){biasD[nbi], biasD[nbi], biasD[nbi], biasD[nbi]};
        }

        #pragma unroll
        for (int ks = 0; ks < 4; ++ks)
            #pragma unroll
            for (int nbi = 0; nbi < 4; ++nbi) {
                cS[nbi] = __builtin_amdgcn_mfma_f32_16x16x32_f16(
                    A[ks], B[0][nbi][ks], cS[nbi], 0, 0, 0);
                cD[nbi] = __builtin_amdgcn_mfma_f32_16x16x32_f16(
                    A[ks], B[1][nbi][ks], cD[nbi], 0, 0, 0);
            }

        #pragma unroll
        for (int nbi = 0; nbi < 4; ++nbi)
            #pragma unroll
            for (int i = 0; i < 4; ++i) {
                const size_t o = (size_t)(row0 + quad * 4 + i) * FF
                               + (half * 4 + nbi) * 16 + lo;
                fs[o] = f2h(cS[nbi][i]);
                fd[o] = f2h(cD[nbi][i]);
            }
    }
}

// =====================================================================
// Fused aggregate, quarter-wave per edge. R12: per-node overhead slimmed
// to packed f16 — val kept as 4x half2v, merged per relation with
// pk2h(rcp(den)) + 4 pk_fma (was 8 cvt + 8 f32 fma); quarter-combine and
// head-mean reductions in packed f16 (half the shfl+add); fast rcp
// (den > 0 guaranteed when mr > 0 since every e = exp(v) > 0).
// =====================================================================
__device__ __forceinline__ void edge4(
    uint4 g, bool ok, const half2v* fdv, const half2v* atv,
    float& den, half2v* acc)
{
    const half2v C02 = {(_Float16)0.2f, (_Float16)0.2f};
    half2v f[4] = {u2h(g.x), u2h(g.y), u2h(g.z), u2h(g.w)};
    float v = 0.f;
    #pragma unroll
    for (int i = 0; i < 4; ++i) {
        const half2v z = f[i] + fdv[i];
        const half2v l = __builtin_elementwise_max(z, z * C02);
        v = dot2(l, atv[i], v);
    }
    v += __shfl_xor(v, 2);
    v += __shfl_xor(v, 1);
    const float e = ok ? __expf(v) : 0.f;
    den += e;
    const half2v eh = pk2h(e);
    #pragma unroll
    for (int i = 0; i < 4; ++i) acc[i] += eh * f[i];
}

__global__ __launch_bounds__(256) void aggregate(
    const int* __restrict__ cnt,             // [R*n]
    const int* __restrict__ slots,           // [R*n][CAP]
    const unsigned* __restrict__ fs_all,     // [R][n][64] f16 pairs
    const unsigned* __restrict__ fd_all,
    const unsigned* __restrict__ att_h,      // this layer: [R][64] f16 pairs
    unsigned* __restrict__ out_h,            // [n][64] or null
    float* __restrict__ out_f32,             // [n][32] or null
    int n)
{
    const int node = blockIdx.x * 4 + (threadIdx.x >> 6);
    if (node >= n) return;
    const int lane = threadIdx.x & 63;
    const int quarter = lane >> 4;
    const int q = lane & 15;
    const int fo = 4 * q;

    int m[4]; int4 sA[4];
    #pragma unroll
    for (int r = 0; r < 4; ++r) {
        const size_t rd = (size_t)r * n + node;
        m[r]  = cnt[rd];
        sA[r] = *(const int4*)&slots[rd * CAP];
    }

    half2v val[4];
    #pragma unroll
    for (int i = 0; i < 4; ++i) val[i] = (half2v){(_Float16)0.f, (_Float16)0.f};

    #pragma unroll
    for (int r = 0; r < 4; ++r) {
        const int mr = m[r];
        if (mr == 0) continue;
        const size_t rd = (size_t)r * n + node;
        const unsigned* fsu = fs_all + (size_t)r * n * 64;

        const int4 sB = *(const int4*)&slots[rd * CAP + 4];
        const uint4 ufd = *(const uint4*)&fd_all[rd * 64 + fo];
        const uint4 uat = *(const uint4*)&att_h[r * 64 + fo];
        half2v fdv[4] = {u2h(ufd.x), u2h(ufd.y), u2h(ufd.z), u2h(ufd.w)};
        half2v atv[4] = {u2h(uat.x), u2h(uat.y), u2h(uat.z), u2h(uat.w)};

        const bool ok0 = quarter < mr;
        const bool ok1 = 4 + quarter < mr;
        int i0 = (quarter == 0) ? sA[r].x : (quarter == 1) ? sA[r].y
               : (quarter == 2) ? sA[r].z : sA[r].w;
        int i1 = (quarter == 0) ? sB.x : (quarter == 1) ? sB.y
               : (quarter == 2) ? sB.z : sB.w;
        i0 = ok0 ? i0 : 0;
        i1 = ok1 ? i1 : 0;
        const uint4 g0 = *(const uint4*)&fsu[(size_t)i0 * 64 + fo];
        const uint4 g1 = *(const uint4*)&fsu[(size_t)i1 * 64 + fo];

        float den = 0.f;
        half2v acc[4];
        #pragma unroll
        for (int i = 0; i < 4; ++i) acc[i] = (half2v){(_Float16)0.f, (_Float16)0.f};

        edge4(g0, ok0, fdv, atv, den, acc);
        if (mr > 4)
            edge4(g1, ok1, fdv, atv, den, acc);

        if (mr > 8) {
            const int* sl = slots + rd * CAP;
            for (int p = 8; p < mr; p += 4) {
                const int ei = p + quarter;
                const bool ok = ei < mr;
                int s = sl[ei < CAP ? ei : CAP - 1]; s = ok ? s : 0;
                const uint4 g = *(const uint4*)&fsu[(size_t)s * 64 + fo];
                edge4(g, ok, fdv, atv, den, acc);
            }
        }

        den += __shfl_xor(den, 16);              // combine quarters' denominators
        den += __shfl_xor(den, 32);
        const half2v ih = pk2h(__builtin_amdgcn_rcpf(den));   // den > 0
        #pragma unroll
        for (int i = 0; i < 4; ++i) val[i] += acc[i] * ih;    // pk_fma
    }

    // combine quarters' numerator contributions (packed)
    #pragma unroll
    for (int i = 0; i < 4; ++i) {
        val[i] = shfladd_h(val[i], 16);
        val[i] = shfladd_h(val[i], 32);
    }

    if (out_f32) {
        // mean over heads: lane q holds feats 8q..8q+7, head = q>>2;
        // orbit q, q^4, q^8, q^12 -> masks 4, 8 (packed)
        #pragma unroll
        for (int i = 0; i < 4; ++i) {
            val[i] = shfladd_h(val[i], 4);
            val[i] = shfladd_h(val[i], 8);
        }
        if (lane < 4) {
            float* o = &out_f32[(size_t)node * 32 + 8 * lane];
            *(float4*)&o[0] = make_float4(0.25f * (float)val[0].x, 0.25f * (float)val[0].y,
                                          0.25f * (float)val[1].x, 0.25f * (float)val[1].y);
            *(float4*)&o[4] = make_float4(0.25f * (float)val[2].x, 0.25f * (float)val[2].y,
                                          0.25f * (float)val[3].x, 0.25f * (float)val[3].y);
        }
    } else {
        if (lane < 16) {
            uint4 o;
            o.x = h2u(val[0]); o.y = h2u(val[1]);
            o.z = h2u(val[2]); o.w = h2u(val[3]);
            *(uint4*)&out_h[(size_t)node * 64 + fo] = o;
        }
    }
}

// =====================================================================
extern "C" void kernel_launch(void* const* d_in, const int* in_sizes, int n_in,
                              void* d_out, int out_size, void* d_ws, size_t ws_size,
                              hipStream_t stream)
{
    const int n  = in_sizes[0] / FF;     // 50000
    const int R  = 4;
    const int ne = in_sizes[1] / R;      // 200000
    const int totalE = R * ne;
    const int L  = R * n;
    const int nrb = (n + 15) / 16;

    const float* x    = (const float*)d_in[0];
    const int*   esrc = (const int*)d_in[1];
    const int*   edst = (const int*)d_in[2];

    // ---- workspace layout (~142 MB of ~268 MB ws) ----
    char* p = (char*)d_ws;
    auto carve = [&p](size_t bytes) { char* q = p; p += (bytes + 255) & ~(size_t)255; return q; };
    unsigned*       hbA    = (unsigned*)      carve((size_t)n * 64 * 4);
    unsigned*       hbB    = (unsigned*)      carve((size_t)n * 64 * 4);
    unsigned short* fs_all = (unsigned short*)carve((size_t)R * n * FF * 2);
    unsigned short* fd_all = (unsigned short*)carve((size_t)R * n * FF * 2);
    unsigned short* Wp     = (unsigned short*)carve((size_t)3 * R * 2 * FF * FF * 2);
    unsigned*       attH   = (unsigned*)      carve((size_t)3 * R * 64 * 4);
    int*            cursor = (int*)           carve((size_t)L * 4);
    int*            slots  = (int*)           carve((size_t)L * CAP * 4);

    (void)hipMemsetAsync(cursor, 0, (size_t)L * sizeof(int), stream);

    // ---- fused setup: gemm0(f32) ⟂ csr_fill ⟂ pack_W ⟂ pack_att ----
    const int CB = (totalE + 1023) / 1024;      // 782 >= GB=512
    setup_fused<<<2 * GB + (CB - GB) + 1536 + 3, 256, 0, stream>>>(
        x,
        (const float*)d_in[3], (const float*)d_in[4],
        (const float*)d_in[5], (const float*)d_in[6],
        fs_all, fd_all, nrb, n,
        esrc, edst, cursor, slots, totalE, ne,
        (const float*)d_in[8],  (const float*)d_in[10],
        (const float*)d_in[13], (const float*)d_in[15],
        Wp,
        (const float*)d_in[7], (const float*)d_in[12], (const float*)d_in[17],
        attH, CB);

    // ---- layers ----
    unsigned* bufs[3] = {hbA, hbB, nullptr};
    for (int l = 0; l < 3; ++l) {
        if (l > 0) {
            const float* bsrc = (const float*)d_in[3 + 5 * l + 1];
            const float* bdst = (const float*)d_in[3 + 5 * l + 3];
            mfma_gemm<<<512, 256, 0, stream>>>(
                (const unsigned short*)bufs[l - 1],
                Wp + (size_t)l * R * 2 * FF * FF,
                bsrc, bdst, fs_all, fd_all, nrb, n);
        }
        const int last = (l == 2);
        aggregate<<<(n + 3) / 4, 256, 0, stream>>>(
            cursor, slots,
            (const unsigned*)fs_all, (const unsigned*)fd_all,
            attH + (size_t)l * R * 64,
            last ? nullptr : bufs[l],
            last ? (float*)d_out : nullptr, n);
    }
}

// Round 13
// 415.671 us; speedup vs baseline: 1.0392x; 1.0392x over previous
//
#include <hip/hip_runtime.h>
#include <math.h>

#define FF 128     // feature width (all layers)
#define CAP 32     // slots per (relation,node); Poisson(4) => P(deg>32) ~ 1e-19
#define GB 512     // gemm blocks inside setup_fused

typedef _Float16 half2v __attribute__((ext_vector_type(2)));
typedef _Float16 f16x8  __attribute__((ext_vector_type(8)));
typedef __fp16   fp16x2 __attribute__((ext_vector_type(2)));
typedef __attribute__((ext_vector_type(4))) float f4v;

__device__ __forceinline__ half2v u2h(unsigned u) {
    union { unsigned u; half2v h; } c; c.u = u; return c.h;
}
__device__ __forceinline__ unsigned h2u(half2v h) {
    union { unsigned u; half2v h; } c; c.h = h; return c.u;
}
__device__ __forceinline__ unsigned short f2h(float f) {
    _Float16 h = (_Float16)f;
    unsigned short u; __builtin_memcpy(&u, &h, 2); return u;
}
__device__ __forceinline__ half2v pk2h(float e) {
    union { fp16x2 p; half2v h; } c;
    c.p = __builtin_amdgcn_cvt_pkrtz(e, e);
    return c.h;
}
__device__ __forceinline__ float dot2(half2v a, half2v b, float c) {
#if __has_builtin(__builtin_amdgcn_fdot2)
    union { half2v h; fp16x2 p; } ca, cb;
    ca.h = a; cb.h = b;
    return __builtin_amdgcn_fdot2(ca.p, cb.p, c, false);
#else
    return c + (float)a.x * (float)b.x + (float)a.y * (float)b.y;
#endif
}
__device__ __forceinline__ half2v shfladd_h(half2v v, int mask) {
    return v + u2h(__shfl_xor(h2u(v), mask));
}
__device__ __forceinline__ int qsel(int4 v, int quarter) {
    return (quarter == 0) ? v.x : (quarter == 1) ? v.y
         : (quarter == 2) ? v.z : v.w;
}

// =====================================================================
// Fused setup dispatch, RANGE-partitioned (R11 structure, measured 108us;
// R12's interleave regressed to 126us — 2 blocks/CU means interleave
// halves gemm residency and the csr path slows under L2 competition):
//   blocks [0, GB)              : layer-0 GEMM, f32 inputs
//   blocks [GB, GB+CB)          : padded-CSR fill, 4 edges/thread
//   blocks [GB+CB, GB+CB+1536)  : pack W -> f16 B-frags
//   last 3 blocks               : pack att
// =====================================================================
__global__ __launch_bounds__(256, 2) void setup_fused(
    const float* __restrict__ x,
    const float* __restrict__ W0s_, const float* __restrict__ bs0,
    const float* __restrict__ W0d_, const float* __restrict__ bd0,
    unsigned short* __restrict__ fs_all, unsigned short* __restrict__ fd_all,
    int nrb, int n,
    const int* __restrict__ esrc_all, const int* __restrict__ edst_all,
    int* __restrict__ cursor, int* __restrict__ slots, int totalE, int ne,
    const float* __restrict__ W1s_, const float* __restrict__ W1d_,
    const float* __restrict__ W2s_, const float* __restrict__ W2d_,
    unsigned short* __restrict__ Wp,
    const float* __restrict__ a0, const float* __restrict__ a1,
    const float* __restrict__ a2, unsigned* __restrict__ attH,
    int CB)
{
    int b = blockIdx.x;
    const int tid = threadIdx.x;

    if (b < GB) {
        // ---------------- layer-0 GEMM (f32 inputs) ----------------
        const int wave = tid >> 6, lane = tid & 63;
        const int r = b & 3;
        const int half = wave & 1;
        const int lo = lane & 15, quad = lane >> 4;

        unsigned short* fs = fs_all + (size_t)r * n * FF;
        unsigned short* fd = fd_all + (size_t)r * n * FF;

        f16x8 B[2][4][4];
        #pragma unroll
        for (int mat = 0; mat < 2; ++mat) {
            const float* W = (mat == 0) ? W0s_ : W0d_;
            #pragma unroll
            for (int nbi = 0; nbi < 4; ++nbi)
                #pragma unroll
                for (int ks = 0; ks < 4; ++ks) {
                    const int nn = (half * 4 + nbi) * 16 + lo;
                    f16x8 v;
                    #pragma unroll
                    for (int j = 0; j < 8; ++j) {
                        const int k = ks * 32 + quad * 8 + j;
                        v[j] = (_Float16)W[((size_t)r * FF + k) * FF + nn];
                    }
                    B[mat][nbi][ks] = v;
                }
        }

        float biasS[4], biasD[4];
        #pragma unroll
        for (int nbi = 0; nbi < 4; ++nbi) {
            biasS[nbi] = bs0[r * FF + (half * 4 + nbi) * 16 + lo];
            biasD[nbi] = bd0[r * FF + (half * 4 + nbi) * 16 + lo];
        }

        const int stride = (GB >> 2) * 2;
        for (int rb = (b >> 2) * 2 + (wave >> 1); rb < nrb; rb += stride) {
            const int row0 = rb * 16;
            f16x8 A[4];
            #pragma unroll
            for (int ks = 0; ks < 4; ++ks) {
                const float* ap = &x[(size_t)(row0 + lo) * FF + ks * 32 + quad * 8];
                const float4 p0 = *(const float4*)&ap[0];
                const float4 p1 = *(const float4*)&ap[4];
                f16x8 v;
                v[0] = (_Float16)p0.x; v[1] = (_Float16)p0.y;
                v[2] = (_Float16)p0.z; v[3] = (_Float16)p0.w;
                v[4] = (_Float16)p1.x; v[5] = (_Float16)p1.y;
                v[6] = (_Float16)p1.z; v[7] = (_Float16)p1.w;
                A[ks] = v;
            }

            f4v cS[4], cD[4];
            #pragma unroll
            for (int nbi = 0; nbi < 4; ++nbi) {
                cS[nbi] = (f4v){biasS[nbi], biasS[nbi], biasS[nbi], biasS[nbi]};
                cD[nbi] = (f4v){biasD[nbi], biasD[nbi], biasD[nbi], biasD[nbi]};
            }

            #pragma unroll
            for (int ks = 0; ks < 4; ++ks)
                #pragma unroll
                for (int nbi = 0; nbi < 4; ++nbi) {
                    cS[nbi] = __builtin_amdgcn_mfma_f32_16x16x32_f16(
                        A[ks], B[0][nbi][ks], cS[nbi], 0, 0, 0);
                    cD[nbi] = __builtin_amdgcn_mfma_f32_16x16x32_f16(
                        A[ks], B[1][nbi][ks], cD[nbi], 0, 0, 0);
                }

            #pragma unroll
            for (int nbi = 0; nbi < 4; ++nbi)
                #pragma unroll
                for (int i = 0; i < 4; ++i) {
                    const size_t o = (size_t)(row0 + quad * 4 + i) * FF
                                   + (half * 4 + nbi) * 16 + lo;
                    fs[o] = f2h(cS[nbi][i]);
                    fd[o] = f2h(cD[nbi][i]);
                }
        }
        return;
    }
    b -= GB;

    if (b < CB) {
        // ---------------- padded-CSR fill, 4 independent chains/thread ----
        const int t0 = b * 1024 + tid;
        #pragma unroll
        for (int k = 0; k < 4; ++k) {
            const int i = t0 + k * 256;
            if (i < totalE) {
                const int r = i / ne;
                const int rd = r * n + edst_all[i];
                const int idx = atomicAdd(&cursor[rd], 1);
                slots[(size_t)rd * CAP + idx] = esrc_all[i];
            }
        }
        return;
    }
    b -= CB;

    if (b < 1536) {
        // ---------------- pack W (all 3 layers) ----------------
        const int t = b * 256 + tid;
        if (t >= 3 * 4 * 2 * FF * FF) return;
        const int l    = t >> 17;
        const int rest = t & 131071;
        const int r    = rest >> 15;
        const int mat  = (rest >> 14) & 1;
        const int idx  = rest & 16383;
        const int k = idx >> 7, nn = idx & 127;
        const float* W = (l == 0) ? (mat ? W0d_ : W0s_)
                       : (l == 1) ? (mat ? W1d_ : W1s_)
                                  : (mat ? W2d_ : W2s_);
        const float v = W[((size_t)r * FF + k) * FF + nn];
        const int nb = nn >> 4, lo = nn & 15;
        const int ks = k >> 5, quad = (k >> 3) & 3, j = k & 7;
        const int lane = quad * 16 + lo;
        const size_t o = (((((((size_t)l * 4 + r) * 2 + mat) * 8 + nb) * 4 + ks) * 64 + lane) * 8) + j;
        Wp[o] = f2h(v);
        return;
    }
    b -= 1536;

    // ---------------- pack att ----------------
    const int t = b * 256 + tid;
    if (t >= 768) return;
    const int l = t >> 8, rest = t & 255;
    const float* a = (l == 0) ? a0 : (l == 1) ? a1 : a2;
    const float2 v = ((const float2*)a)[rest];
    half2v h = {(_Float16)v.x, (_Float16)v.y};
    attH[t] = h2u(h);
}

// =====================================================================
// Batched MFMA GEMM over all 4 relations, f16 inputs (layers 1,2).
// Verified R8/R9, unchanged.
// =====================================================================
__global__ __launch_bounds__(256, 2) void mfma_gemm(
    const unsigned short* __restrict__ hb,
    const unsigned short* __restrict__ Wp,
    const float* __restrict__ bs_all,
    const float* __restrict__ bd_all,
    unsigned short* __restrict__ fs_all,
    unsigned short* __restrict__ fd_all,
    int nrb, int n)
{
    const int wave = threadIdx.x >> 6, lane = threadIdx.x & 63;
    const int r = blockIdx.x & 3;
    const int half = wave & 1;
    const int lo = lane & 15, quad = lane >> 4;

    const unsigned short* Wr = Wp + (size_t)r * 2 * FF * FF;
    unsigned short* fs = fs_all + (size_t)r * n * FF;
    unsigned short* fd = fd_all + (size_t)r * n * FF;

    f16x8 B[2][4][4];
    #pragma unroll
    for (int mat = 0; mat < 2; ++mat)
        #pragma unroll
        for (int nbi = 0; nbi < 4; ++nbi)
            #pragma unroll
            for (int ks = 0; ks < 4; ++ks) {
                const int nb = half * 4 + nbi;
                B[mat][nbi][ks] = *(const f16x8*)
                    &Wr[(((((size_t)mat * 8 + nb) * 4 + ks) * 64 + lane) * 8)];
            }

    float biasS[4], biasD[4];
    #pragma unroll
    for (int nbi = 0; nbi < 4; ++nbi) {
        biasS[nbi] = bs_all[r * FF + (half * 4 + nbi) * 16 + lo];
        biasD[nbi] = bd_all[r * FF + (half * 4 + nbi) * 16 + lo];
    }

    const int stride = (gridDim.x >> 2) * 2;
    for (int rb = (blockIdx.x >> 2) * 2 + (wave >> 1); rb < nrb; rb += stride) {
        const int row0 = rb * 16;
        f16x8 A[4];
        #pragma unroll
        for (int ks = 0; ks < 4; ++ks)
            A[ks] = *(const f16x8*)&hb[(size_t)(row0 + lo) * FF + ks * 32 + quad * 8];

        f4v cS[4], cD[4];
        #pragma unroll
        for (int nbi = 0; nbi < 4; ++nbi) {
            cS[nbi] = (f4v){biasS[nbi], biasS[nbi], biasS[nbi], biasS[nbi]};
            cD[nbi] = (f4v){biasD[nbi], biasD[nbi], biasD[nbi], biasD[nbi]};
        }

        #pragma unroll
        for (int ks = 0; ks < 4; ++ks)
            #pragma unroll
            for (int nbi = 0; nbi < 4; ++nbi) {
                cS[nbi] = __builtin_amdgcn_mfma_f32_16x16x32_f16(
                    A[ks], B[0][nbi][ks], cS[nbi], 0, 0, 0);
                cD[nbi] = __builtin_amdgcn_mfma_f32_16x16x32_f16(
                    A[ks], B[1][nbi][ks], cD[nbi], 0, 0, 0);
            }

        #pragma unroll
        for (int nbi = 0; nbi < 4; ++nbi)
            #pragma unroll
            for (int i = 0; i < 4; ++i) {
                const size_t o = (size_t)(row0 + quad * 4 + i) * FF
                               + (half * 4 + nbi) * 16 + lo;
                fs[o] = f2h(cS[nbi][i]);
                fd[o] = f2h(cD[nbi][i]);
            }
    }
}

// =====================================================================
// Fused aggregate, quarter-wave per edge. R13: relations processed in
// PAIRS (0,1) then (2,3) with both relations' metadata + first-8 gathers
// issued back-to-back BEFORE any consumption — doubles gather MLP (the
// r-serial version stalls each relation's gathers behind the previous
// relation's den-reduction). Packed-f16 epilogue kept from R12.
// =====================================================================
__device__ __forceinline__ void edge4(
    uint4 g, bool ok, const half2v* fdv, const half2v* atv,
    float& den, half2v* acc)
{
    const half2v C02 = {(_Float16)0.2f, (_Float16)0.2f};
    half2v f[4] = {u2h(g.x), u2h(g.y), u2h(g.z), u2h(g.w)};
    float v = 0.f;
    #pragma unroll
    for (int i = 0; i < 4; ++i) {
        const half2v z = f[i] + fdv[i];
        const half2v l = __builtin_elementwise_max(z, z * C02);
        v = dot2(l, atv[i], v);
    }
    v += __shfl_xor(v, 2);
    v += __shfl_xor(v, 1);
    const float e = ok ? __expf(v) : 0.f;
    den += e;
    const half2v eh = pk2h(e);
    #pragma unroll
    for (int i = 0; i < 4; ++i) acc[i] += eh * f[i];
}

__global__ __launch_bounds__(256) void aggregate(
    const int* __restrict__ cnt,             // [R*n]
    const int* __restrict__ slots,           // [R*n][CAP]
    const unsigned* __restrict__ fs_all,     // [R][n][64] f16 pairs
    const unsigned* __restrict__ fd_all,
    const unsigned* __restrict__ att_h,      // this layer: [R][64] f16 pairs
    unsigned* __restrict__ out_h,            // [n][64] or null
    float* __restrict__ out_f32,             // [n][32] or null
    int n)
{
    const int node = blockIdx.x * 4 + (threadIdx.x >> 6);
    if (node >= n) return;
    const int lane = threadIdx.x & 63;
    const int quarter = lane >> 4;
    const int q = lane & 15;
    const int fo = 4 * q;

    int m[4]; int4 sA[4];
    #pragma unroll
    for (int r = 0; r < 4; ++r) {
        const size_t rd = (size_t)r * n + node;
        m[r]  = cnt[rd];
        sA[r] = *(const int4*)&slots[rd * CAP];
    }

    half2v val[4];
    #pragma unroll
    for (int i = 0; i < 4; ++i) val[i] = (half2v){(_Float16)0.f, (_Float16)0.f};

    #pragma unroll
    for (int rp = 0; rp < 2; ++rp) {
        const int ra = 2 * rp, rb = 2 * rp + 1;
        const size_t rdA = (size_t)ra * n + node;
        const size_t rdB = (size_t)rb * n + node;
        const int mA = m[ra], mB = m[rb];
        const unsigned* fsuA = fs_all + (size_t)ra * n * 64;
        const unsigned* fsuB = fs_all + (size_t)rb * n * 64;

        // ---- issue ALL loads for both relations up front ----
        const int4 sBA = *(const int4*)&slots[rdA * CAP + 4];
        const int4 sBB = *(const int4*)&slots[rdB * CAP + 4];
        const uint4 ufdA = *(const uint4*)&fd_all[rdA * 64 + fo];
        const uint4 ufdB = *(const uint4*)&fd_all[rdB * 64 + fo];
        const uint4 uatA = *(const uint4*)&att_h[ra * 64 + fo];
        const uint4 uatB = *(const uint4*)&att_h[rb * 64 + fo];

        const bool okA0 = quarter < mA, okA1 = 4 + quarter < mA;
        const bool okB0 = quarter < mB, okB1 = 4 + quarter < mB;
        int iA0 = qsel(sA[ra], quarter); iA0 = okA0 ? iA0 : 0;
        int iB0 = qsel(sA[rb], quarter); iB0 = okB0 ? iB0 : 0;
        int iA1 = qsel(sBA, quarter);    iA1 = okA1 ? iA1 : 0;
        int iB1 = qsel(sBB, quarter);    iB1 = okB1 ? iB1 : 0;
        const uint4 gA0 = *(const uint4*)&fsuA[(size_t)iA0 * 64 + fo];
        const uint4 gB0 = *(const uint4*)&fsuB[(size_t)iB0 * 64 + fo];
        const uint4 gA1 = *(const uint4*)&fsuA[(size_t)iA1 * 64 + fo];
        const uint4 gB1 = *(const uint4*)&fsuB[(size_t)iB1 * 64 + fo];

        half2v fdvA[4] = {u2h(ufdA.x), u2h(ufdA.y), u2h(ufdA.z), u2h(ufdA.w)};
        half2v atvA[4] = {u2h(uatA.x), u2h(uatA.y), u2h(uatA.z), u2h(uatA.w)};
        half2v fdvB[4] = {u2h(ufdB.x), u2h(ufdB.y), u2h(ufdB.z), u2h(ufdB.w)};
        half2v atvB[4] = {u2h(uatB.x), u2h(uatB.y), u2h(uatB.z), u2h(uatB.w)};

        float denA = 0.f, denB = 0.f;
        half2v accA[4], accB[4];
        #pragma unroll
        for (int i = 0; i < 4; ++i) {
            accA[i] = (half2v){(_Float16)0.f, (_Float16)0.f};
            accB[i] = (half2v){(_Float16)0.f, (_Float16)0.f};
        }

        edge4(gA0, okA0, fdvA, atvA, denA, accA);
        edge4(gB0, okB0, fdvB, atvB, denB, accB);
        if (mA > 4) edge4(gA1, okA1, fdvA, atvA, denA, accA);
        if (mB > 4) edge4(gB1, okB1, fdvB, atvB, denB, accB);

        if (mA > 8) {                        // P ~ 2%
            const int* sl = slots + rdA * CAP;
            for (int p = 8; p < mA; p += 4) {
                const int ei = p + quarter;
                const bool ok = ei < mA;
                int s = sl[ei < CAP ? ei : CAP - 1]; s = ok ? s : 0;
                const uint4 g = *(const uint4*)&fsuA[(size_t)s * 64 + fo];
                edge4(g, ok, fdvA, atvA, denA, accA);
            }
        }
        if (mB > 8) {
            const int* sl = slots + rdB * CAP;
            for (int p = 8; p < mB; p += 4) {
                const int ei = p + quarter;
                const bool ok = ei < mB;
                int s = sl[ei < CAP ? ei : CAP - 1]; s = ok ? s : 0;
                const uint4 g = *(const uint4*)&fsuB[(size_t)s * 64 + fo];
                edge4(g, ok, fdvB, atvB, denB, accB);
            }
        }

        if (mA) {
            denA += __shfl_xor(denA, 16);
            denA += __shfl_xor(denA, 32);
            const half2v ih = pk2h(__builtin_amdgcn_rcpf(denA));   // denA > 0
            #pragma unroll
            for (int i = 0; i < 4; ++i) val[i] += accA[i] * ih;
        }
        if (mB) {
            denB += __shfl_xor(denB, 16);
            denB += __shfl_xor(denB, 32);
            const half2v ih = pk2h(__builtin_amdgcn_rcpf(denB));   // denB > 0
            #pragma unroll
            for (int i = 0; i < 4; ++i) val[i] += accB[i] * ih;
        }
    }

    // combine quarters' numerator contributions (packed)
    #pragma unroll
    for (int i = 0; i < 4; ++i) {
        val[i] = shfladd_h(val[i], 16);
        val[i] = shfladd_h(val[i], 32);
    }

    if (out_f32) {
        // mean over heads: lane q holds feats 8q..8q+7, head = q>>2;
        // orbit masks 4, 8 (packed)
        #pragma unroll
        for (int i = 0; i < 4; ++i) {
            val[i] = shfladd_h(val[i], 4);
            val[i] = shfladd_h(val[i], 8);
        }
        if (lane < 4) {
            float* o = &out_f32[(size_t)node * 32 + 8 * lane];
            *(float4*)&o[0] = make_float4(0.25f * (float)val[0].x, 0.25f * (float)val[0].y,
                                          0.25f * (float)val[1].x, 0.25f * (float)val[1].y);
            *(float4*)&o[4] = make_float4(0.25f * (float)val[2].x, 0.25f * (float)val[2].y,
                                          0.25f * (float)val[3].x, 0.25f * (float)val[3].y);
        }
    } else {
        if (lane < 16) {
            uint4 o;
            o.x = h2u(val[0]); o.y = h2u(val[1]);
            o.z = h2u(val[2]); o.w = h2u(val[3]);
            *(uint4*)&out_h[(size_t)node * 64 + fo] = o;
        }
    }
}

// =====================================================================
extern "C" void kernel_launch(void* const* d_in, const int* in_sizes, int n_in,
                              void* d_out, int out_size, void* d_ws, size_t ws_size,
                              hipStream_t stream)
{
    const int n  = in_sizes[0] / FF;     // 50000
    const int R  = 4;
    const int ne = in_sizes[1] / R;      // 200000
    const int totalE = R * ne;
    const int L  = R * n;
    const int nrb = (n + 15) / 16;

    const float* x    = (const float*)d_in[0];
    const int*   esrc = (const int*)d_in[1];
    const int*   edst = (const int*)d_in[2];

    // ---- workspace layout (~142 MB of ~268 MB ws) ----
    char* p = (char*)d_ws;
    auto carve = [&p](size_t bytes) { char* q = p; p += (bytes + 255) & ~(size_t)255; return q; };
    unsigned*       hbA    = (unsigned*)      carve((size_t)n * 64 * 4);
    unsigned*       hbB    = (unsigned*)      carve((size_t)n * 64 * 4);
    unsigned short* fs_all = (unsigned short*)carve((size_t)R * n * FF * 2);
    unsigned short* fd_all = (unsigned short*)carve((size_t)R * n * FF * 2);
    unsigned short* Wp     = (unsigned short*)carve((size_t)3 * R * 2 * FF * FF * 2);
    unsigned*       attH   = (unsigned*)      carve((size_t)3 * R * 64 * 4);
    int*            cursor = (int*)           carve((size_t)L * 4);
    int*            slots  = (int*)           carve((size_t)L * CAP * 4);

    (void)hipMemsetAsync(cursor, 0, (size_t)L * sizeof(int), stream);

    // ---- fused setup: gemm0(f32) + csr_fill + pack_W + pack_att ----
    const int CB = (totalE + 1023) / 1024;
    setup_fused<<<GB + CB + 1536 + 3, 256, 0, stream>>>(
        x,
        (const float*)d_in[3], (const float*)d_in[4],
        (const float*)d_in[5], (const float*)d_in[6],
        fs_all, fd_all, nrb, n,
        esrc, edst, cursor, slots, totalE, ne,
        (const float*)d_in[8],  (const float*)d_in[10],
        (const float*)d_in[13], (const float*)d_in[15],
        Wp,
        (const float*)d_in[7], (const float*)d_in[12], (const float*)d_in[17],
        attH, CB);

    // ---- layers ----
    unsigned* bufs[3] = {hbA, hbB, nullptr};
    for (int l = 0; l < 3; ++l) {
        if (l > 0) {
            const float* bsrc = (const float*)d_in[3 + 5 * l + 1];
            const float* bdst = (const float*)d_in[3 + 5 * l + 3];
            mfma_gemm<<<512, 256, 0, stream>>>(
                (const unsigned short*)bufs[l - 1],
                Wp + (size_t)l * R * 2 * FF * FF,
                bsrc, bdst, fs_all, fd_all, nrb, n);
        }
        const int last = (l == 2);
        aggregate<<<(n + 3) / 4, 256, 0, stream>>>(
            cursor, slots,
            (const unsigned*)fs_all, (const unsigned*)fd_all,
            attH + (size_t)l * R * 64,
            last ? nullptr : bufs[l],
            last ? (float*)d_out : nullptr, n);
    }
}